// Round 1
// 400.582 us; speedup vs baseline: 1.0109x; 1.0109x over previous
//
#include <hip/hip_runtime.h>

// Problem constants (fixed by reference): B=4, S=2048, DIN=4096, DOUT=4096
#define GM 8192   // M = B*S
#define GN 4096   // N = DOUT
#define GK 4096   // K = DIN

#define BM 128
#define BN 256
#define BK 64             // bytes of K per tile (i8)
#define NT (GK / BK)      // 64 K-tiles
#define ATILE (BM * BK)                 // 8192 B
#define TILE_LDS (BM * BK + BN * BK)    // 24576 B per buffer

using int4v = __attribute__((ext_vector_type(4))) int;

// ---------------- fused quantization ----------------
// x path: x_int8 = (int)(x * input_scale)      -- trunc toward zero
// w path: w_int8 = (int)rintf(w * wscale[row]) -- round half-even
__global__ __launch_bounds__(256) void quant_xw_k(
    const float4* __restrict__ x, unsigned int* __restrict__ xq,
    const float4* __restrict__ w, unsigned int* __restrict__ wq,
    const float* __restrict__ wscale, const float* __restrict__ iscale,
    int n4x, int n4tot) {
    const float xs = *iscale;
    const int stride = gridDim.x * blockDim.x;
    for (int i = blockIdx.x * blockDim.x + threadIdx.x; i < n4tot; i += stride) {
        if (i < n4x) {
            float4 v = x[i];
            int q0 = (int)(v.x * xs);
            int q1 = (int)(v.y * xs);
            int q2 = (int)(v.z * xs);
            int q3 = (int)(v.w * xs);
            xq[i] = (unsigned int)(q0 & 0xff)
                  | ((unsigned int)(q1 & 0xff) << 8)
                  | ((unsigned int)(q2 & 0xff) << 16)
                  | ((unsigned int)(q3 & 0xff) << 24);
        } else {
            int j = i - n4x;
            float s = wscale[j >> 10];          // 1024 float4 per 4096-f32 row
            float4 v = w[j];
            int q0 = (int)rintf(v.x * s);
            int q1 = (int)rintf(v.y * s);
            int q2 = (int)rintf(v.z * s);
            int q3 = (int)rintf(v.w * s);
            wq[j] = (unsigned int)(q0 & 0xff)
                  | ((unsigned int)(q1 & 0xff) << 8)
                  | ((unsigned int)(q2 & 0xff) << 16)
                  | ((unsigned int)(q3 & 0xff) << 24);
        }
    }
}

// ---------------- int8 GEMM ----------------
// Block tile 128x256, BK=64. 4 waves, each computes 64x128 (4x8 of 16x16x64).
// LDS XOR-swizzle (unchanged, conflict-free: SQ_LDS_BANK_CONFLICT==0):
//   chunk (row,kc) of a tile stored at row*64 + (kc ^ ((row>>1)&3))*16,
//   realized by permuting the per-lane *global source* chunk (global_load_lds
//   writes linearly at base + lane*16).
//
// NEW: triple-buffered pipeline with counted vmcnt — T3/T4/T5.
//   iteration t: issue 6 GLL for tile t+2 into buf[(t+2)%3] (held tile t-1,
//   retired by the end-of-(t-1) barrier), ds_read+MFMA tile t from buf[t%3],
//   then s_waitcnt vmcnt(6) (waits ONLY tile t+1's 6 loads; t+2's stay in
//   flight across the barrier) + raw s_barrier. One barrier per K-step,
//   no vmcnt(0)/lgkmcnt(0) drain anywhere in the loop.
__global__ __launch_bounds__(256, 2) void qlinear_gemm_i8(
    const signed char* __restrict__ Aq,
    const signed char* __restrict__ Bq,
    const float* __restrict__ bias,
    const float* __restrict__ wscale,
    const float* __restrict__ iscale,
    float* __restrict__ C) {
    __shared__ signed char smem[3][TILE_LDS];   // 3 x 24 KiB = 72 KiB

    const int tid  = threadIdx.x;
    const int wave = tid >> 6;
    const int lane = tid & 63;
    const int m0 = blockIdx.x * BM;
    const int n0 = blockIdx.y * BN;
    const int wm = (wave >> 1) * 64;     // {0,64}
    const int wn = (wave & 1) * 128;     // {0,128}

    int4v acc[4][8];
#pragma unroll
    for (int i = 0; i < 4; ++i)
#pragma unroll
        for (int j = 0; j < 8; ++j)
            acc[i][j] = int4v{0, 0, 0, 0};

    // --- staging addresses (identical swizzle to verified kernel)
    const int kcl = (((lane & 3) ^ ((lane >> 3) & 3))) * 16;
    const int segA = wave * 2;
    const signed char* gA0 = Aq + (size_t)(m0 + segA * 16 + (lane >> 2)) * GK + kcl;
    const int aoff = segA * 1024 + lane * 16;
    const int segB = wave * 4;
    const signed char* gB0 = Bq + (size_t)(n0 + segB * 16 + (lane >> 2)) * GK + kcl;
    const int boff = ATILE + segB * 1024 + lane * 16;

    // --- LDS fragment read offsets (identical to verified kernel)
    const int pos = ((lane >> 4) ^ ((lane >> 1) & 3)) * 16;
    const int fAoff = (wm + (lane & 15)) * BK + pos;
    const int fBoff = ATILE + (wn + (lane & 15)) * BK + pos;

#define GLL16(g, l)                                                     \
    __builtin_amdgcn_global_load_lds(                                   \
        (__attribute__((address_space(1))) void*)(void*)(g),            \
        (__attribute__((address_space(3))) void*)(void*)(l), 16, 0, 0)

#define STAGE(kb, sb)                                                   \
    do {                                                                \
        GLL16(gA0 + (size_t)(kb), (sb) + aoff);                         \
        GLL16(gA0 + (size_t)16 * GK + (kb), (sb) + aoff + 1024);        \
        GLL16(gB0 + (size_t)(kb), (sb) + boff);                         \
        GLL16(gB0 + (size_t)16 * GK + (kb), (sb) + boff + 1024);        \
        GLL16(gB0 + (size_t)32 * GK + (kb), (sb) + boff + 2048);        \
        GLL16(gB0 + (size_t)48 * GK + (kb), (sb) + boff + 3072);        \
    } while (0)

    // --- prologue: stage tiles 0 and 1; wait tile 0 only (vmcnt 6 = tile 1
    // still in flight), rendezvous.
    STAGE(0, smem[0]);
    STAGE(BK, smem[1]);
    asm volatile("s_waitcnt vmcnt(6)" ::: "memory");
    __builtin_amdgcn_s_barrier();
    __builtin_amdgcn_sched_barrier(0);

    int cur = 0;           // buffer holding tile t
    int kstage = 2 * BK;   // byte-k of tile t+2 (wraps to harmless re-reads)
    for (int t = 0; t < NT; ++t) {
        int nb = cur + 2; if (nb >= 3) nb -= 3;
        STAGE(kstage, smem[nb]);            // tile t+2 -> buffer of tile t-1
        kstage += BK; if (kstage >= GK) kstage = 0;
        __builtin_amdgcn_sched_barrier(0);  // pin GLL issue before compute

        const signed char* sb = smem[cur];
        int4v a[4], b[8];
#pragma unroll
        for (int i = 0; i < 4; ++i)
            a[i] = *(const int4v*)(sb + fAoff + i * 16 * BK);
#pragma unroll
        for (int j = 0; j < 8; ++j)
            b[j] = *(const int4v*)(sb + fBoff + j * 16 * BK);

        __builtin_amdgcn_s_setprio(1);
#pragma unroll
        for (int mi = 0; mi < 4; ++mi)
#pragma unroll
            for (int ni = 0; ni < 8; ++ni)
                acc[mi][ni] = __builtin_amdgcn_mfma_i32_16x16x64_i8(
                    a[mi], b[ni], acc[mi][ni], 0, 0, 0);
        __builtin_amdgcn_s_setprio(0);

        // retire tile t+1's 6 loads only; tile t+2's 6 stay in flight
        asm volatile("s_waitcnt vmcnt(6)" ::: "memory");
        __builtin_amdgcn_s_barrier();
        __builtin_amdgcn_sched_barrier(0);
        cur += 1; if (cur == 3) cur = 0;
    }

    // --- epilogue (unchanged): C/D layout col=lane&15, row=(lane>>4)*4+reg
    const float isc = *iscale;
#pragma unroll
    for (int ni = 0; ni < 8; ++ni) {
        const int col = n0 + wn + ni * 16 + (lane & 15);
        const float bs = bias[col];
        const float inv = 1.0f / (wscale[col] * isc);
#pragma unroll
        for (int mi = 0; mi < 4; ++mi) {
            const int row0 = m0 + wm + mi * 16 + (lane >> 4) * 4;
#pragma unroll
            for (int r = 0; r < 4; ++r) {
                C[(size_t)(row0 + r) * GN + col] =
                    ((float)acc[mi][ni][r] + bs) * inv;
            }
        }
    }
#undef STAGE
#undef GLL16
}

extern "C" void kernel_launch(void* const* d_in, const int* in_sizes, int n_in,
                              void* d_out, int out_size, void* d_ws, size_t ws_size,
                              hipStream_t stream) {
    const float* x      = (const float*)d_in[0];  // (4,2048,4096)
    const float* w      = (const float*)d_in[1];  // (4096,4096)
    const float* bias   = (const float*)d_in[2];  // (4096,)
    const float* wscale = (const float*)d_in[3];  // (4096,)
    const float* iscale = (const float*)d_in[4];  // (1,)
    float* out = (float*)d_out;

    signed char* xq = (signed char*)d_ws;                       // 32 MiB
    signed char* wq = xq + (size_t)GM * GK;                     // 16 MiB

    const int n4x = GM * GK / 4;
    const int n4w = GN * GK / 4;
    quant_xw_k<<<3072, 256, 0, stream>>>((const float4*)x, (unsigned int*)xq,
                                         (const float4*)w, (unsigned int*)wq,
                                         wscale, iscale, n4x, n4x + n4w);

    dim3 grid(GM / BM, GN / BN);   // 64 x 16 = 1024 blocks
    qlinear_gemm_i8<<<grid, 256, 0, stream>>>(xq, wq, bias, wscale, iscale, out);
}

// Round 2
// 399.615 us; speedup vs baseline: 1.0134x; 1.0024x over previous
//
#include <hip/hip_runtime.h>

// Problem constants (fixed by reference): B=4, S=2048, DIN=4096, DOUT=4096
#define GM 8192   // M = B*S
#define GN 4096   // N = DOUT
#define GK 4096   // K = DIN

#define BM 256
#define BN 256
#define BK 64             // bytes of K per tile (i8)
#define NTILE (GK / BK)   // 64 K-tiles
#define ABYTES (BM * BK)              // 16384 per K-tile
#define TILE_LDS (BM * BK + BN * BK)  // 32768 per K-tile buffer

using int4v = __attribute__((ext_vector_type(4))) int;

// ---------------- fused quantization ----------------
// x path: x_int8 = (int)(x * input_scale)      -- trunc toward zero
// w path: w_int8 = (int)rintf(w * wscale[row]) -- round half-even
__global__ __launch_bounds__(256) void quant_xw_k(
    const float4* __restrict__ x, unsigned int* __restrict__ xq,
    const float4* __restrict__ w, unsigned int* __restrict__ wq,
    const float* __restrict__ wscale, const float* __restrict__ iscale,
    int n4x, int n4tot) {
    const float xs = *iscale;
    const int stride = gridDim.x * blockDim.x;
    for (int i = blockIdx.x * blockDim.x + threadIdx.x; i < n4tot; i += stride) {
        if (i < n4x) {
            float4 v = x[i];
            int q0 = (int)(v.x * xs);
            int q1 = (int)(v.y * xs);
            int q2 = (int)(v.z * xs);
            int q3 = (int)(v.w * xs);
            xq[i] = (unsigned int)(q0 & 0xff)
                  | ((unsigned int)(q1 & 0xff) << 8)
                  | ((unsigned int)(q2 & 0xff) << 16)
                  | ((unsigned int)(q3 & 0xff) << 24);
        } else {
            int j = i - n4x;
            float s = wscale[j >> 10];          // 1024 float4 per 4096-f32 row
            float4 v = w[j];
            int q0 = (int)rintf(v.x * s);
            int q1 = (int)rintf(v.y * s);
            int q2 = (int)rintf(v.z * s);
            int q3 = (int)rintf(v.w * s);
            wq[j] = (unsigned int)(q0 & 0xff)
                  | ((unsigned int)(q1 & 0xff) << 8)
                  | ((unsigned int)(q2 & 0xff) << 16)
                  | ((unsigned int)(q3 & 0xff) << 24);
        }
    }
}

// ---------------- int8 GEMM: 256x256 tile, 8 waves, phase-split schedule ----
// Wave (2M x 4N) owns a 128x64 output: acc[8][4] of 16x16.
// K-tile = 64 B; per tile two phases:
//   P1: ds_read A-reps 0..3 + B-reps 0..3 | stage A(t+2) | 16 MFMA (M-lo x N)
//   P2: ds_read A-reps 4..7               | stage B(t+2) | 16 MFMA (M-hi x N)
// 3 K-tile LDS buffers (96 KiB), prefetch distance 2; ONE counted
// s_waitcnt vmcnt(4) per K-tile (retires tile t+1; tile t+2's 4 loads stay in
// flight across the barrier). Never drains in-loop.
//
// Swizzle (verified conflict-free in prior rounds, row stride 64 B):
//   stored chunk slot s of row r holds logical chunk s ^ ((r>>1)&3);
//   global_load_lds writes linearly, so the *source* chunk per thread is
//   permuted: kc = (tid&3) ^ ((tid>>3)&3); reads use
//   pos = ((lane>>4) ^ ((lane>>1)&3))*16.
__global__ __launch_bounds__(512, 2) void qlinear_gemm_i8(
    const signed char* __restrict__ Aq,
    const signed char* __restrict__ Bq,
    const float* __restrict__ bias,
    const float* __restrict__ wscale,
    const float* __restrict__ iscale,
    float* __restrict__ C) {
    __shared__ signed char smem[3 * TILE_LDS];   // 96 KiB

    const int tid  = threadIdx.x;
    const int wave = tid >> 6;
    const int lane = tid & 63;
    const int m0 = blockIdx.x * BM;
    const int n0 = blockIdx.y * BN;
    const int wm = (wave >> 2) * 128;    // {0,128}
    const int wn = (wave & 3) * 64;      // {0,64,128,192}

    int4v acc[8][4];
#pragma unroll
    for (int i = 0; i < 8; ++i)
#pragma unroll
        for (int j = 0; j < 4; ++j)
            acc[i][j] = int4v{0, 0, 0, 0};

    // --- staging: 512 threads cover 128 rows x 64 B per GLL round
    const int kc = ((tid & 3) ^ ((tid >> 3) & 3)) * 16;   // swizzled src chunk
    const signed char* gA = Aq + (size_t)(m0 + (tid >> 2)) * GK + kc;
    const signed char* gB = Bq + (size_t)(n0 + (tid >> 2)) * GK + kc;
    const int dst = tid * 16;                             // linear LDS dest

    // --- LDS fragment read offsets (within one K-tile buffer)
    const int pos = (((lane >> 4) ^ ((lane >> 1) & 3))) * 16;
    const int fAo = (wm + (lane & 15)) * BK + pos;            // + mi*1024
    const int fBo = ABYTES + (wn + (lane & 15)) * BK + pos;   // + ni*1024

#define GLL16(g, l)                                                     \
    __builtin_amdgcn_global_load_lds(                                   \
        (__attribute__((address_space(1))) void*)(void*)(g),            \
        (__attribute__((address_space(3))) void*)(void*)(l), 16, 0, 0)

#define STAGE_A(kb, soff)                                               \
    do {                                                                \
        GLL16(gA + (kb), smem + (soff) + dst);                          \
        GLL16(gA + (size_t)128 * GK + (kb), smem + (soff) + 8192 + dst);\
    } while (0)
#define STAGE_B(kb, soff)                                               \
    do {                                                                \
        GLL16(gB + (kb), smem + (soff) + ABYTES + dst);                 \
        GLL16(gB + (size_t)128 * GK + (kb),                             \
              smem + (soff) + ABYTES + 8192 + dst);                     \
    } while (0)

    // --- prologue: stage tiles 0 and 1; retire tile 0 only (vmcnt 4 leaves
    // tile 1's 4 loads in flight), rendezvous.
    STAGE_A(0, 0);
    STAGE_B(0, 0);
    STAGE_A(BK, TILE_LDS);
    STAGE_B(BK, TILE_LDS);
    asm volatile("s_waitcnt vmcnt(4)" ::: "memory");
    __builtin_amdgcn_s_barrier();
    __builtin_amdgcn_sched_barrier(0);

    int bc = 0;                 // buffer byte-offset of tile t
    int bn2 = TILE_LDS;         // tile t+1
    int bs = 2 * TILE_LDS;      // stage target (tile t+2)
    int kst = 2 * BK;           // k-byte of tile t+2 (wraps: harmless re-read)
    for (int t = 0; t < NTILE; ++t) {
        const signed char* fA = smem + bc + fAo;
        const signed char* fB = smem + bc + fBo;
        int4v aF[4], bF[4], aG[4];

        // ---------------- phase 1: M-lo quadrant ----------------
#pragma unroll
        for (int i = 0; i < 4; ++i)
            aF[i] = *(const int4v*)(fA + i * 1024);
#pragma unroll
        for (int j = 0; j < 4; ++j)
            bF[j] = *(const int4v*)(fB + j * 1024);
        STAGE_A(kst, bs);                 // A(t+2)
        __builtin_amdgcn_s_barrier();
        asm volatile("s_waitcnt lgkmcnt(0)" ::: "memory");
        __builtin_amdgcn_sched_barrier(0);
        __builtin_amdgcn_s_setprio(1);
#pragma unroll
        for (int i = 0; i < 4; ++i)
#pragma unroll
            for (int j = 0; j < 4; ++j)
                acc[i][j] = __builtin_amdgcn_mfma_i32_16x16x64_i8(
                    aF[i], bF[j], acc[i][j], 0, 0, 0);
        __builtin_amdgcn_s_setprio(0);
        __builtin_amdgcn_s_barrier();
        __builtin_amdgcn_sched_barrier(0);

        // ---------------- phase 2: M-hi quadrant ----------------
#pragma unroll
        for (int i = 0; i < 4; ++i)
            aG[i] = *(const int4v*)(fA + (i + 4) * 1024);
        STAGE_B(kst, bs);                 // B(t+2)
        __builtin_amdgcn_s_barrier();
        asm volatile("s_waitcnt lgkmcnt(0)" ::: "memory");
        __builtin_amdgcn_sched_barrier(0);
        __builtin_amdgcn_s_setprio(1);
#pragma unroll
        for (int i = 0; i < 4; ++i)
#pragma unroll
            for (int j = 0; j < 4; ++j)
                acc[i + 4][j] = __builtin_amdgcn_mfma_i32_16x16x64_i8(
                    aG[i], bF[j], acc[i + 4][j], 0, 0, 0);
        __builtin_amdgcn_s_setprio(0);
        // retire tile t+1's 4 loads; tile t+2's 4 stay in flight
        asm volatile("s_waitcnt vmcnt(4)" ::: "memory");
        __builtin_amdgcn_s_barrier();
        __builtin_amdgcn_sched_barrier(0);

        // rotate buffers; advance stage-k
        int tmp = bc; bc = bn2; bn2 = bs; bs = tmp;
        kst += BK; if (kst >= GK) kst = 0;
    }

    // --- epilogue: C/D layout col=lane&15, row=(lane>>4)*4+reg
    const float isc = *iscale;
#pragma unroll
    for (int ni = 0; ni < 4; ++ni) {
        const int col = n0 + wn + ni * 16 + (lane & 15);
        const float bs_ = bias[col];
        const float inv = 1.0f / (wscale[col] * isc);
#pragma unroll
        for (int mi = 0; mi < 8; ++mi) {
            const int row0 = m0 + wm + mi * 16 + (lane >> 4) * 4;
#pragma unroll
            for (int r = 0; r < 4; ++r) {
                C[(size_t)(row0 + r) * GN + col] =
                    ((float)acc[mi][ni][r] + bs_) * inv;
            }
        }
    }
#undef STAGE_A
#undef STAGE_B
#undef GLL16
}

extern "C" void kernel_launch(void* const* d_in, const int* in_sizes, int n_in,
                              void* d_out, int out_size, void* d_ws, size_t ws_size,
                              hipStream_t stream) {
    const float* x      = (const float*)d_in[0];  // (4,2048,4096)
    const float* w      = (const float*)d_in[1];  // (4096,4096)
    const float* bias   = (const float*)d_in[2];  // (4096,)
    const float* wscale = (const float*)d_in[3];  // (4096,)
    const float* iscale = (const float*)d_in[4];  // (1,)
    float* out = (float*)d_out;

    signed char* xq = (signed char*)d_ws;                       // 32 MiB
    signed char* wq = xq + (size_t)GM * GK;                     // 16 MiB

    const int n4x = GM * GK / 4;
    const int n4w = GN * GK / 4;
    quant_xw_k<<<3072, 256, 0, stream>>>((const float4*)x, (unsigned int*)xq,
                                         (const float4*)w, (unsigned int*)wq,
                                         wscale, iscale, n4x, n4x + n4w);

    dim3 grid(GM / BM, GN / BN);   // 32 x 16 = 512 blocks
    qlinear_gemm_i8<<<grid, 512, 0, stream>>>(xq, wq, bias, wscale, iscale, out);
}